// Round 1
// baseline (884.804 us; speedup 1.0000x reference)
//
#include <hip/hip_runtime.h>
#include <hip/hip_bf16.h>
#include <cstdint>
#include <cstddef>

using bf16 = __hip_bfloat16;
using short8 = __attribute__((ext_vector_type(8))) short;
using floatx4 = __attribute__((ext_vector_type(4))) float;

constexpr int D_IN = 1024;
constexpr int H_DIM = 4096;
constexpr int E_NUM = 8;
constexpr int NTOK = 8192;   // B*S
constexpr int NPAIR = NTOK * 2;
constexpr int MAXT = 136;    // sum ceil(cnt_e/128) <= 135; multiple of 8 (XCD map)

// ---------------- workspace layout (bytes) ----------------
constexpr size_t OFF_PTOK  = 1024;
constexpr size_t OFF_PPROB = 263168;
constexpr size_t OFF_SCHED = 525312;
constexpr size_t OFF_XBF   = 1048576;
constexpr size_t OFF_W2T   = OFF_XBF + (size_t)NTOK * D_IN * 2;
constexpr size_t OFF_HBUF  = OFF_W2T + (size_t)E_NUM * D_IN * H_DIM * 2;
constexpr size_t OFF_W1T   = OFF_HBUF + (size_t)NPAIR * H_DIM * 2;

__device__ __forceinline__ void cp16(const bf16* g, bf16* s) {
  __builtin_amdgcn_global_load_lds(
      (const __attribute__((address_space(1))) unsigned int*)g,
      (__attribute__((address_space(3))) unsigned int*)s, 16, 0, 0);
}

// ---------- fp32 [K,N] -> bf16 [N,K] transposed convert, 64x64 tiles ----------
__global__ __launch_bounds__(256) void transpose_cvt(
    const float* __restrict__ in, bf16* __restrict__ out, int K, int N) {
  __shared__ float tile[64][65];
  const int e = blockIdx.z;
  const float* ip = in + (size_t)e * K * N + (size_t)(blockIdx.y * 64) * N + blockIdx.x * 64;
  bf16* op = out + (size_t)e * K * N + (size_t)(blockIdx.x * 64) * K + blockIdx.y * 64;
  const int tc = threadIdx.x & 15;   // col group (4 floats)
  const int tr = threadIdx.x >> 4;   // row 0..15
#pragma unroll
  for (int r = 0; r < 4; r++) {
    const float4 v = *(const float4*)&ip[(size_t)(tr + r * 16) * N + tc * 4];
    *(float4*)&tile[tr + r * 16][tc * 4] = v;
  }
  __syncthreads();
  const int kg = threadIdx.x & 7;    // k-group of 8
  const int nb = threadIdx.x >> 3;   // 0..31
#pragma unroll
  for (int r = 0; r < 2; r++) {
    const int n = nb + r * 32;
    union { short8 v; bf16 h[8]; } u;
#pragma unroll
    for (int j = 0; j < 8; j++) u.h[j] = __float2bfloat16(tile[kg * 8 + j][n]);
    *(short8*)&op[(size_t)n * K + kg * 8] = u.v;
  }
}

// ------- router: logits, softmax, top-2, x->bf16; hierarchical atomics ------
__global__ __launch_bounds__(256) void router_kernel(
    const float* __restrict__ x, const float* __restrict__ Wg,
    const float* __restrict__ bg, bf16* __restrict__ Xbf,
    int* __restrict__ counts, int* __restrict__ pairTok, float* __restrict__ pairProb) {
  __shared__ int lcnt[E_NUM];
  __shared__ int sBase[E_NUM];
  __shared__ int sE0[32], sL0[32], sE1[32], sL1[32];
  __shared__ float sP0[32], sP1[32];
  const int lane = threadIdx.x & 63;
  const int wave = threadIdx.x >> 6;
  if (threadIdx.x < E_NUM) lcnt[threadIdx.x] = 0;
  __syncthreads();

  for (int tk = 0; tk < 8; tk++) {
    const int li = wave * 8 + tk;
    const int n = blockIdx.x * 32 + li;
    const float* xr = x + (size_t)n * D_IN;
    bf16* xbr = Xbf + (size_t)n * D_IN;
    float logit[E_NUM];
#pragma unroll
    for (int e = 0; e < E_NUM; e++) logit[e] = 0.f;
#pragma unroll
    for (int i = 0; i < 16; i++) {
      const int d = i * 64 + lane;
      const float xd = xr[d];
      xbr[d] = __float2bfloat16(xd);
      const float4* wr = (const float4*)(Wg + (size_t)d * E_NUM);
      const float4 w0 = wr[0], w1 = wr[1];
      logit[0] += xd * w0.x; logit[1] += xd * w0.y;
      logit[2] += xd * w0.z; logit[3] += xd * w0.w;
      logit[4] += xd * w1.x; logit[5] += xd * w1.y;
      logit[6] += xd * w1.z; logit[7] += xd * w1.w;
    }
#pragma unroll
    for (int e = 0; e < E_NUM; e++) {
#pragma unroll
      for (int off = 32; off >= 1; off >>= 1)
        logit[e] += __shfl_xor(logit[e], off, 64);
    }
    if (lane == 0) {
      float l[E_NUM], mx = -1e30f;
#pragma unroll
      for (int e = 0; e < E_NUM; e++) { l[e] = logit[e] + bg[e]; mx = fmaxf(mx, l[e]); }
      float ex[E_NUM], s = 0.f;
#pragma unroll
      for (int e = 0; e < E_NUM; e++) { ex[e] = expf(l[e] - mx); s += ex[e]; }
      int i0 = 0;
#pragma unroll
      for (int e = 1; e < E_NUM; e++) if (l[e] > l[i0]) i0 = e;
      int i1 = (i0 == 0) ? 1 : 0;
#pragma unroll
      for (int e = 0; e < E_NUM; e++) if (e != i0 && l[e] > l[i1]) i1 = e;
      const float inv = 1.f / s;
      sE0[li] = i0; sL0[li] = atomicAdd(&lcnt[i0], 1); sP0[li] = ex[i0] * inv;
      sE1[li] = i1; sL1[li] = atomicAdd(&lcnt[i1], 1); sP1[li] = ex[i1] * inv;
    }
  }
  __syncthreads();
  if (threadIdx.x < E_NUM)
    sBase[threadIdx.x] = atomicAdd(&counts[threadIdx.x], lcnt[threadIdx.x]);
  __syncthreads();
  if (threadIdx.x < 32) {
    const int li = threadIdx.x;
    const int n = blockIdx.x * 32 + li;
    const int e0 = sE0[li], p0 = sBase[e0] + sL0[li];
    pairTok[e0 * NTOK + p0] = n;               // slot 0
    pairProb[e0 * NTOK + p0] = sP0[li];
    const int e1 = sE1[li], p1 = sBase[e1] + sL1[li];
    pairTok[e1 * NTOK + p1] = n | (1 << 15);   // slot 1
    pairProb[e1 * NTOK + p1] = sP1[li];
  }
}

// ---------------- tile scheduler: exact (expert, m-tile) list ----------------
__global__ void sched_kernel(const int* __restrict__ counts, int* __restrict__ sched) {
  if (threadIdx.x == 0 && blockIdx.x == 0) {
    int* bases = sched;
    int* nTiles = sched + 8;
    int* tileMap = sched + 16;
    int base = 0, t = 0;
    for (int e = 0; e < E_NUM; e++) {
      bases[e] = base;
      const int nt = (counts[e] + 127) >> 7;
      for (int m = 0; m < nt; m++) tileMap[t++] = (e << 16) | m;
      base += counts[e];
    }
    *nTiles = t;
  }
}

// ---------------- grouped GEMM, 128x128, BK=32, 16x16x32 bf16 MFMA ----------
// 3-ring LDS pipeline with counted vmcnt (T3/T4): compute K-tile t from ring
// t%3 while staging K-tile t+3 into the same ring (issued only after all
// waves' reads of that ring retired: lgkmcnt(0)+barrier). s_waitcnt vmcnt(8)
// at group end retires exactly stage(t+1); stage(t+2)/(t+3) stay in flight
// across the barrier -- never drain to 0 in the loop.
// T2: LDS 16B-chunk XOR swizzle (chunk ^= row&3). global_load_lds writes
// linearly, so the swizzle is applied to the per-lane GLOBAL source chunk
// (inverse == same XOR) and to the ds_read address.  -> conflict-free b128.
// T5: setprio(1) around the MFMA cluster.
// Tail groups keep staging past K (<=96B into the next workspace region,
// staged-but-never-read), keeping vmcnt arithmetic uniform.
// bid = nb*MAXT + tix (MAXT%8==0) => XCD = tix%8: all n-blocks (and k-splits)
// of an (expert,m-tile) share one XCD -> A tile served from that XCD's L2.
// MODE 0: Hout[base+p][n] = gelu(Xbf[tok[p]] @ W1t[e]^T + b1[e])
// MODE 1: KS-way K-split; atomicAdd(out[tok][n], (acc + (ks==0)*b2[e][n])*prob)
template <int MODE, int K, int NC, int KS>
__global__ __launch_bounds__(256, 3) void gemm_kernel(
    const bf16* __restrict__ A, const bf16* __restrict__ Wt,
    const float* __restrict__ bias, const int* __restrict__ counts,
    const int* __restrict__ pairTok, const float* __restrict__ pairProb,
    const int* __restrict__ sched, bf16* __restrict__ Hout, float* __restrict__ out) {
  const int tix = blockIdx.x % MAXT;
  int nb = blockIdx.x / MAXT;
  if (tix >= sched[8]) return;
  int ks = 0;
  if (MODE == 1) { ks = nb >> 3; nb &= 7; }
  constexpr int KJOB = K / KS;       // K range per job
  constexpr int NT = KJOB / 32;      // K-tiles per job
  const int ksOff = ks * KJOB;

  const int packed = sched[16 + tix];
  const int e = packed >> 16;
  const int m0 = (packed & 0xFFFF) * 128;
  const int cnt = counts[e];
  const int base = sched[e];
  const int n0 = nb * 128;

  __shared__ __align__(16) bf16 As[3 * 128 * 32];   // 3 rings x 8KB
  __shared__ __align__(16) bf16 Bs[3 * 128 * 32];

  const int t = threadIdx.x;
  const int lane = t & 63;
  const int wave = t >> 6;
  const int wm = wave >> 1, wn = wave & 1;        // 2x2 wave grid, 64x64 each
  const int fr = lane & 15;
  // swizzled chunk select for ds_read: want global chunk kg=(lane>>4);
  // LDS chunk = kg ^ (row&3), and row&3 == lane&3 for all fragments.
  const int csel = ((lane >> 4) ^ (lane & 3)) << 3;       // elems
  const int aBase = (wm * 64 + fr) * 32 + csel;           // + mf*512
  const int bBase = (wn * 64 + fr) * 32 + csel;           // + nf*512

  // Staging: thread owns chunks li = t and 256+t of A-tile and of B-tile.
  // li -> (row = li>>2, s = li&3); LDS dest elem = li*8 (linear => valid for
  // global_load_lds); global source chunk = s ^ (row&3)  (XOR involution).
  const int r0 = t >> 2, r1 = 64 + (t >> 2);              // r1&3 == r0&3
  const int gc = (((t & 3) ^ (r0 & 3)) << 3);             // elems
  int p0 = m0 + r0; if (p0 > cnt - 1) p0 = cnt - 1;       // clamp ragged tail
  int p1 = m0 + r1; if (p1 > cnt - 1) p1 = cnt - 1;
  const bf16 *aS0, *aS1;
  if (MODE == 0) {
    aS0 = A + (size_t)(pairTok[e * NTOK + p0] & 0x1FFF) * K + gc;
    aS1 = A + (size_t)(pairTok[e * NTOK + p1] & 0x1FFF) * K + gc;
  } else {
    aS0 = A + (size_t)(base + p0) * K + ksOff + gc;
    aS1 = A + (size_t)(base + p1) * K + ksOff + gc;
  }
  const bf16* bS0 = Wt + ((size_t)e * NC + n0 + r0) * K + ksOff + gc;
  const bf16* bS1 = Wt + ((size_t)e * NC + n0 + r1) * K + ksOff + gc;

  floatx4 acc[4][4];
#pragma unroll
  for (int ti = 0; ti < 4; ti++)
#pragma unroll
    for (int tj = 0; tj < 4; tj++)
      acc[ti][tj] = {0.f, 0.f, 0.f, 0.f};

  // prologue: stage rings 0..2 (12 loads/thread), wait ring0 (newest 8 live)
#pragma unroll
  for (int q = 0; q < 3; q++) {
    cp16(aS0 + q * 32, &As[q * 4096 + t * 8]);
    cp16(aS1 + q * 32, &As[q * 4096 + 2048 + t * 8]);
    cp16(bS0 + q * 32, &Bs[q * 4096 + t * 8]);
    cp16(bS1 + q * 32, &Bs[q * 4096 + 2048 + t * 8]);
  }
  asm volatile("s_waitcnt vmcnt(8)" ::: "memory");
  __builtin_amdgcn_sched_barrier(0);
  __builtin_amdgcn_s_barrier();
  __builtin_amdgcn_sched_barrier(0);

  int rb = 0;                         // ring base (elems)
#pragma unroll 1
  for (int kt = 0; kt < NT; kt++) {
    short8 a[4], b[4];
#pragma unroll
    for (int i = 0; i < 4; i++) {
      a[i] = *(const short8*)&As[rb + aBase + i * 512];
      b[i] = *(const short8*)&Bs[rb + bBase + i * 512];
    }
    // my reads of ring rb retired; barrier => ALL waves' reads retired
    asm volatile("s_waitcnt lgkmcnt(0)" ::: "memory");
    __builtin_amdgcn_sched_barrier(0);
    __builtin_amdgcn_s_barrier();
    __builtin_amdgcn_sched_barrier(0);
    // stage K-tile kt+3 into this ring (lands >= next iteration; read kt+3)
    const int kq = (kt + 3) * 32;
    cp16(aS0 + kq, &As[rb + t * 8]);
    cp16(aS1 + kq, &As[rb + 2048 + t * 8]);
    cp16(bS0 + kq, &Bs[rb + t * 8]);
    cp16(bS1 + kq, &Bs[rb + 2048 + t * 8]);
    __builtin_amdgcn_s_setprio(1);
#pragma unroll
    for (int ti = 0; ti < 4; ti++)
#pragma unroll
      for (int tj = 0; tj < 4; tj++)
        acc[ti][tj] = __builtin_amdgcn_mfma_f32_16x16x32_bf16(a[ti], b[tj], acc[ti][tj], 0, 0, 0);
    __builtin_amdgcn_s_setprio(0);
    // retire stage(kt+1): outstanding <=12, newest 8 = stage(kt+2),(kt+3)
    asm volatile("s_waitcnt vmcnt(8)" ::: "memory");
    __builtin_amdgcn_sched_barrier(0);
    __builtin_amdgcn_s_barrier();
    __builtin_amdgcn_sched_barrier(0);
    rb += 4096;
    if (rb == 12288) rb = 0;
  }

  float bv[4];
#pragma unroll
  for (int tj = 0; tj < 4; tj++)
    bv[tj] = bias[(size_t)e * NC + n0 + wn * 64 + tj * 16 + fr];

#pragma unroll
  for (int ti = 0; ti < 4; ti++) {
    const int rbrow = wm * 64 + ti * 16 + (lane >> 4) * 4;
#pragma unroll
    for (int i = 0; i < 4; i++) {
      const int p = m0 + rbrow + i;
      if (p < cnt) {
        if (MODE == 0) {
          bf16* orow = Hout + (size_t)(base + p) * NC + n0 + wn * 64 + fr;
#pragma unroll
          for (int tj = 0; tj < 4; tj++) {
            const float h = acc[ti][tj][i] + bv[tj];
            const float g = 0.5f * h * (1.f + erff(h * 0.70710678118f));
            orow[tj * 16] = __float2bfloat16(g);
          }
        } else {
          const int pt = pairTok[e * NTOK + p];
          const float pr = pairProb[e * NTOK + p];
          const int tok = pt & 0x1FFF;
          float* orow = out + (size_t)tok * NC + n0 + wn * 64 + fr;
#pragma unroll
          for (int tj = 0; tj < 4; tj++) {
            float v = acc[ti][tj][i];
            if (ks == 0) v += bv[tj];
            atomicAdd(&orow[tj * 16], v * pr);
          }
        }
      }
    }
  }
}

extern "C" void kernel_launch(void* const* d_in, const int* in_sizes, int n_in,
                              void* d_out, int out_size, void* d_ws, size_t ws_size,
                              hipStream_t stream) {
  const float* x  = (const float*)d_in[0];
  const float* Wg = (const float*)d_in[1];
  const float* bg = (const float*)d_in[2];
  const float* W1 = (const float*)d_in[3];
  const float* b1 = (const float*)d_in[4];
  const float* W2 = (const float*)d_in[5];
  const float* b2 = (const float*)d_in[6];
  float* out = (float*)d_out;
  char* ws = (char*)d_ws;

  int*   counts   = (int*)ws;
  int*   pairTok  = (int*)(ws + OFF_PTOK);
  float* pairProb = (float*)(ws + OFF_PPROB);
  int*   sched    = (int*)(ws + OFF_SCHED);
  bf16*  Xbf      = (bf16*)(ws + OFF_XBF);
  bf16*  W2t      = (bf16*)(ws + OFF_W2T);
  bf16*  Hbuf     = (bf16*)(ws + OFF_HBUF);
  bf16*  W1t      = (bf16*)(ws + OFF_W1T);

  hipMemsetAsync(counts, 0, 64, stream);
  hipMemsetAsync(out, 0, (size_t)NTOK * D_IN * sizeof(float), stream);
  // W1 [E][1024][4096] -> W1t [E][4096][1024]
  transpose_cvt<<<dim3(H_DIM / 64, D_IN / 64, E_NUM), 256, 0, stream>>>(W1, W1t, D_IN, H_DIM);
  // W2 [E][4096][1024] -> W2t [E][1024][4096]
  transpose_cvt<<<dim3(D_IN / 64, H_DIM / 64, E_NUM), 256, 0, stream>>>(W2, W2t, H_DIM, D_IN);
  router_kernel<<<NTOK / 32, 256, 0, stream>>>(x, Wg, bg, Xbf, counts, pairTok, pairProb);
  sched_kernel<<<1, 64, 0, stream>>>(counts, sched);
  gemm_kernel<0, D_IN, H_DIM, 1><<<32 * MAXT, 256, 0, stream>>>(
      Xbf, W1t, b1, counts, pairTok, pairProb, sched, Hbuf, nullptr);
  gemm_kernel<1, H_DIM, D_IN, 2><<<16 * MAXT, 256, 0, stream>>>(
      Hbuf, W2t, b2, counts, pairTok, pairProb, sched, nullptr, out);
}

// Round 2
// 821.228 us; speedup vs baseline: 1.0774x; 1.0774x over previous
//
#include <hip/hip_runtime.h>
#include <hip/hip_bf16.h>
#include <cstdint>
#include <cstddef>

using bf16 = __hip_bfloat16;
using short8 = __attribute__((ext_vector_type(8))) short;
using floatx4 = __attribute__((ext_vector_type(4))) float;

constexpr int D_IN = 1024;
constexpr int H_DIM = 4096;
constexpr int E_NUM = 8;
constexpr int NTOK = 8192;   // B*S
constexpr int NPAIR = NTOK * 2;
constexpr int MAXT = 136;    // sum ceil(cnt_e/128) <= 135; 136 = 34 m-supers * 4

// ---------------- workspace layout (bytes) ----------------
constexpr size_t OFF_PTOK  = 1024;
constexpr size_t OFF_PPROB = 263168;
constexpr size_t OFF_SCHED = 525312;
constexpr size_t OFF_XBF   = 1048576;
constexpr size_t OFF_W2T   = OFF_XBF + (size_t)NTOK * D_IN * 2;
constexpr size_t OFF_HBUF  = OFF_W2T + (size_t)E_NUM * D_IN * H_DIM * 2;
constexpr size_t OFF_W1T   = OFF_HBUF + (size_t)NPAIR * H_DIM * 2;

__device__ __forceinline__ void cp16(const bf16* g, bf16* s) {
  __builtin_amdgcn_global_load_lds(
      (const __attribute__((address_space(1))) unsigned int*)g,
      (__attribute__((address_space(3))) unsigned int*)s, 16, 0, 0);
}

// ---------- fp32 [K,N] -> bf16 [N,K] transposed convert, 64x64 tiles ----------
__global__ __launch_bounds__(256) void transpose_cvt(
    const float* __restrict__ in, bf16* __restrict__ out, int K, int N) {
  __shared__ float tile[64][65];
  const int e = blockIdx.z;
  const float* ip = in + (size_t)e * K * N + (size_t)(blockIdx.y * 64) * N + blockIdx.x * 64;
  bf16* op = out + (size_t)e * K * N + (size_t)(blockIdx.x * 64) * K + blockIdx.y * 64;
  const int tc = threadIdx.x & 15;   // col group (4 floats)
  const int tr = threadIdx.x >> 4;   // row 0..15
#pragma unroll
  for (int r = 0; r < 4; r++) {
    const float4 v = *(const float4*)&ip[(size_t)(tr + r * 16) * N + tc * 4];
    *(float4*)&tile[tr + r * 16][tc * 4] = v;
  }
  __syncthreads();
  const int kg = threadIdx.x & 7;    // k-group of 8
  const int nb = threadIdx.x >> 3;   // 0..31
#pragma unroll
  for (int r = 0; r < 2; r++) {
    const int n = nb + r * 32;
    union { short8 v; bf16 h[8]; } u;
#pragma unroll
    for (int j = 0; j < 8; j++) u.h[j] = __float2bfloat16(tile[kg * 8 + j][n]);
    *(short8*)&op[(size_t)n * K + kg * 8] = u.v;
  }
}

// ------- router: logits, softmax, top-2, x->bf16; hierarchical atomics ------
__global__ __launch_bounds__(256) void router_kernel(
    const float* __restrict__ x, const float* __restrict__ Wg,
    const float* __restrict__ bg, bf16* __restrict__ Xbf,
    int* __restrict__ counts, int* __restrict__ pairTok, float* __restrict__ pairProb) {
  __shared__ int lcnt[E_NUM];
  __shared__ int sBase[E_NUM];
  __shared__ int sE0[32], sL0[32], sE1[32], sL1[32];
  __shared__ float sP0[32], sP1[32];
  const int lane = threadIdx.x & 63;
  const int wave = threadIdx.x >> 6;
  if (threadIdx.x < E_NUM) lcnt[threadIdx.x] = 0;
  __syncthreads();

  for (int tk = 0; tk < 8; tk++) {
    const int li = wave * 8 + tk;
    const int n = blockIdx.x * 32 + li;
    const float* xr = x + (size_t)n * D_IN;
    bf16* xbr = Xbf + (size_t)n * D_IN;
    float logit[E_NUM];
#pragma unroll
    for (int e = 0; e < E_NUM; e++) logit[e] = 0.f;
#pragma unroll
    for (int i = 0; i < 16; i++) {
      const int d = i * 64 + lane;
      const float xd = xr[d];
      xbr[d] = __float2bfloat16(xd);
      const float4* wr = (const float4*)(Wg + (size_t)d * E_NUM);
      const float4 w0 = wr[0], w1 = wr[1];
      logit[0] += xd * w0.x; logit[1] += xd * w0.y;
      logit[2] += xd * w0.z; logit[3] += xd * w0.w;
      logit[4] += xd * w1.x; logit[5] += xd * w1.y;
      logit[6] += xd * w1.z; logit[7] += xd * w1.w;
    }
#pragma unroll
    for (int e = 0; e < E_NUM; e++) {
#pragma unroll
      for (int off = 32; off >= 1; off >>= 1)
        logit[e] += __shfl_xor(logit[e], off, 64);
    }
    if (lane == 0) {
      float l[E_NUM], mx = -1e30f;
#pragma unroll
      for (int e = 0; e < E_NUM; e++) { l[e] = logit[e] + bg[e]; mx = fmaxf(mx, l[e]); }
      float ex[E_NUM], s = 0.f;
#pragma unroll
      for (int e = 0; e < E_NUM; e++) { ex[e] = expf(l[e] - mx); s += ex[e]; }
      int i0 = 0;
#pragma unroll
      for (int e = 1; e < E_NUM; e++) if (l[e] > l[i0]) i0 = e;
      int i1 = (i0 == 0) ? 1 : 0;
#pragma unroll
      for (int e = 0; e < E_NUM; e++) if (e != i0 && l[e] > l[i1]) i1 = e;
      const float inv = 1.f / s;
      sE0[li] = i0; sL0[li] = atomicAdd(&lcnt[i0], 1); sP0[li] = ex[i0] * inv;
      sE1[li] = i1; sL1[li] = atomicAdd(&lcnt[i1], 1); sP1[li] = ex[i1] * inv;
    }
  }
  __syncthreads();
  if (threadIdx.x < E_NUM)
    sBase[threadIdx.x] = atomicAdd(&counts[threadIdx.x], lcnt[threadIdx.x]);
  __syncthreads();
  if (threadIdx.x < 32) {
    const int li = threadIdx.x;
    const int n = blockIdx.x * 32 + li;
    const int e0 = sE0[li], p0 = sBase[e0] + sL0[li];
    pairTok[e0 * NTOK + p0] = n;               // slot 0
    pairProb[e0 * NTOK + p0] = sP0[li];
    const int e1 = sE1[li], p1 = sBase[e1] + sL1[li];
    pairTok[e1 * NTOK + p1] = n | (1 << 15);   // slot 1
    pairProb[e1 * NTOK + p1] = sP1[li];
  }
}

// ---------------- tile scheduler: exact (expert, m-tile) list ----------------
__global__ void sched_kernel(const int* __restrict__ counts, int* __restrict__ sched) {
  if (threadIdx.x == 0 && blockIdx.x == 0) {
    int* bases = sched;
    int* nTiles = sched + 8;
    int* tileMap = sched + 16;
    int base = 0, t = 0;
    for (int e = 0; e < E_NUM; e++) {
      bases[e] = base;
      const int nt = (counts[e] + 127) >> 7;
      for (int m = 0; m < nt; m++) tileMap[t++] = (e << 16) | m;
      base += counts[e];
    }
    *nTiles = t;
  }
}

// ---------------- grouped GEMM, 128x128, BK=32, 16x16x32 bf16 MFMA ----------
// Supertile XCD scheduling: HW maps blockIdx -> XCD as bid%8. Each XCD gets a
// contiguous chunk of supertiles; one supertile = 4 m-tiles x 8 n-blocks = 32
// blocks (bids base+8j+xcd), working set 4x256KB A + 8x256KB B = 3MB ~ L2.
// Consecutive supertiles in a chunk share A-panels (4 ns per ms) -> L2 reuse
// of BOTH operands (round-1 mapping only reused the small A).
// Register-pipelined single-barrier K-loop (T3/T4): frags of tile kt live in
// regs; per iter: waitcnt(vmcnt(4),lgkm(0)) -> barrier -> stage tile kt+3 into
// ring kt%3 -> ds_read tile kt+1 frags -> MFMA tile kt. ds_read latency hides
// under MFMA; staging loads never drain to 0 (vmcnt(4): tiles kt+2,kt+3 stay
// in flight). Stage offset clamped to KJOB-32 (no tail over-read).
// MODE 0: Hout[base+p][n] = gelu(Xbf[tok[p]] @ W1t[e]^T + b1[e])
// MODE 1: KS-way K-split; atomicAdd(out[tok][n], (acc + (ks==0)*b2[e][n])*prob)
template <int MODE, int K, int NC, int KS>
__global__ __launch_bounds__(256, 3) void gemm_kernel(
    const bf16* __restrict__ A, const bf16* __restrict__ Wt,
    const float* __restrict__ bias, const int* __restrict__ counts,
    const int* __restrict__ pairTok, const float* __restrict__ pairProb,
    const int* __restrict__ sched, bf16* __restrict__ Hout, float* __restrict__ out) {
  constexpr int KJOB = K / KS;
  constexpr int NT = KJOB / 32;

  const int xcd = blockIdx.x & 7;
  const int loc = blockIdx.x >> 3;
  const int sg  = loc >> 5;
  const int j   = loc & 31;
  int tix, nb, ks = 0;
  if (MODE == 0) {
    const int st = xcd * 17 + sg;            // 136 supertiles (34 ms x 4 ns)
    tix = (st >> 2) * 4 + (j >> 3);
    nb  = (st & 3) * 8 + (j & 7);
  } else {
    const int st = xcd * 9 + sg;             // 68 supertiles (2 ks x 34 ms); grid padded to 72
    if (st >= 68) return;
    ks  = st >= 34 ? 1 : 0;
    tix = (st - ks * 34) * 4 + (j >> 3);
    nb  = j & 7;
  }
  if (tix >= sched[8]) return;
  const int ksOff = ks * KJOB;

  const int packed = sched[16 + tix];
  const int e = packed >> 16;
  const int m0 = (packed & 0xFFFF) * 128;
  const int cnt = counts[e];
  const int base = sched[e];
  const int n0 = nb * 128;

  __shared__ __align__(16) bf16 As[3 * 128 * 32];   // 3 rings x 8KB
  __shared__ __align__(16) bf16 Bs[3 * 128 * 32];

  const int t = threadIdx.x;
  const int lane = t & 63;
  const int wave = t >> 6;
  const int wm = wave >> 1, wn = wave & 1;        // 2x2 wave grid, 64x64 each
  const int fr = lane & 15;
  const int kg = (lane >> 4) << 3;                // k-chunk of 8 elems
  const int aBase = (wm * 64 + fr) * 32 + kg;     // + ti*512
  const int bBase = (wn * 64 + fr) * 32 + kg;     // + tj*512

  // Staging: thread owns 16B chunks t and 256+t of the A-tile and B-tile.
  // chunk li -> row = li>>2, kchunk = li&3; LDS dest = li*8 (linear).
  const int r0 = t >> 2, r1 = 64 + (t >> 2);
  const int gc = (t & 3) << 3;                    // elems
  int p0 = m0 + r0; if (p0 > cnt - 1) p0 = cnt - 1;   // clamp ragged tail
  int p1 = m0 + r1; if (p1 > cnt - 1) p1 = cnt - 1;
  const bf16 *aS0, *aS1;
  if (MODE == 0) {
    aS0 = A + (size_t)(pairTok[e * NTOK + p0] & 0x1FFF) * K + gc;
    aS1 = A + (size_t)(pairTok[e * NTOK + p1] & 0x1FFF) * K + gc;
  } else {
    aS0 = A + (size_t)(base + p0) * K + ksOff + gc;
    aS1 = A + (size_t)(base + p1) * K + ksOff + gc;
  }
  const bf16* bS0 = Wt + ((size_t)e * NC + n0 + r0) * K + ksOff + gc;
  const bf16* bS1 = Wt + ((size_t)e * NC + n0 + r1) * K + ksOff + gc;

  floatx4 acc[4][4];
#pragma unroll
  for (int ti = 0; ti < 4; ti++)
#pragma unroll
    for (int tj = 0; tj < 4; tj++)
      acc[ti][tj] = {0.f, 0.f, 0.f, 0.f};

  // prologue: stage tiles 0..2 into rings 0..2; wait tile0; read its frags
#pragma unroll
  for (int q = 0; q < 3; q++) {
    cp16(aS0 + q * 32, &As[q * 4096 + t * 8]);
    cp16(aS1 + q * 32, &As[q * 4096 + 2048 + t * 8]);
    cp16(bS0 + q * 32, &Bs[q * 4096 + t * 8]);
    cp16(bS1 + q * 32, &Bs[q * 4096 + 2048 + t * 8]);
  }
  asm volatile("s_waitcnt vmcnt(8)" ::: "memory");
  __builtin_amdgcn_sched_barrier(0);
  __builtin_amdgcn_s_barrier();
  __builtin_amdgcn_sched_barrier(0);

  short8 aC[4], bC[4], aN[4], bN[4];
#pragma unroll
  for (int i = 0; i < 4; i++) {
    aC[i] = *(const short8*)&As[aBase + i * 512];
    bC[i] = *(const short8*)&Bs[bBase + i * 512];
  }

  auto step = [&](int kt, int rbW, int rbR, short8 (&ac)[4], short8 (&bc)[4],
                  short8 (&an)[4], short8 (&bn)[4]) {
    // tile kt frags (ac/bc) read-complete + tile kt+1 resident in LDS
    asm volatile("s_waitcnt vmcnt(4) lgkmcnt(0)" ::: "memory");
    __builtin_amdgcn_sched_barrier(0);
    __builtin_amdgcn_s_barrier();
    __builtin_amdgcn_sched_barrier(0);
    // stage tile kt+3 into ring kt%3 (tile kt's frags are in regs now)
    int kq = (kt + 3) * 32;
    if (kq > KJOB - 32) kq = KJOB - 32;   // clamp: restage last k-tile, no OOB
    cp16(aS0 + kq, &As[rbW + t * 8]);
    cp16(aS1 + kq, &As[rbW + 2048 + t * 8]);
    cp16(bS0 + kq, &Bs[rbW + t * 8]);
    cp16(bS1 + kq, &Bs[rbW + 2048 + t * 8]);
    // issue tile kt+1 frag reads (no wait); MFMA tile kt overlaps them
#pragma unroll
    for (int i = 0; i < 4; i++) {
      an[i] = *(const short8*)&As[rbR + aBase + i * 512];
      bn[i] = *(const short8*)&Bs[rbR + bBase + i * 512];
    }
    __builtin_amdgcn_s_setprio(1);
#pragma unroll
    for (int ti = 0; ti < 4; ti++)
#pragma unroll
      for (int tj = 0; tj < 4; tj++)
        acc[ti][tj] = __builtin_amdgcn_mfma_f32_16x16x32_bf16(ac[ti], bc[tj], acc[ti][tj], 0, 0, 0);
    __builtin_amdgcn_s_setprio(0);
  };

  int rbW = 0, rbR = 4096;
#pragma unroll 1
  for (int kt = 0; kt < NT; kt += 2) {
    step(kt, rbW, rbR, aC, bC, aN, bN);
    rbW = rbR; rbR += 4096; if (rbR == 12288) rbR = 0;
    step(kt + 1, rbW, rbR, aN, bN, aC, bC);
    rbW = rbR; rbR += 4096; if (rbR == 12288) rbR = 0;
  }

  float bv[4];
#pragma unroll
  for (int tj = 0; tj < 4; tj++)
    bv[tj] = bias[(size_t)e * NC + n0 + wn * 64 + tj * 16 + fr];

#pragma unroll
  for (int ti = 0; ti < 4; ti++) {
    const int rbrow = wm * 64 + ti * 16 + (lane >> 4) * 4;
#pragma unroll
    for (int i = 0; i < 4; i++) {
      const int p = m0 + rbrow + i;
      if (p < cnt) {
        if (MODE == 0) {
          bf16* orow = Hout + (size_t)(base + p) * NC + n0 + wn * 64 + fr;
#pragma unroll
          for (int tj = 0; tj < 4; tj++) {
            const float h = acc[ti][tj][i] + bv[tj];
            const float g = 0.5f * h * (1.f + erff(h * 0.70710678118f));
            orow[tj * 16] = __float2bfloat16(g);
          }
        } else {
          const int pt = pairTok[e * NTOK + p];
          const float pr = pairProb[e * NTOK + p];
          const int tok = pt & 0x1FFF;
          float* orow = out + (size_t)tok * NC + n0 + wn * 64 + fr;
#pragma unroll
          for (int tj = 0; tj < 4; tj++) {
            float v = acc[ti][tj][i];
            if (ks == 0) v += bv[tj];
            atomicAdd(&orow[tj * 16], v * pr);
          }
        }
      }
    }
  }
}

extern "C" void kernel_launch(void* const* d_in, const int* in_sizes, int n_in,
                              void* d_out, int out_size, void* d_ws, size_t ws_size,
                              hipStream_t stream) {
  const float* x  = (const float*)d_in[0];
  const float* Wg = (const float*)d_in[1];
  const float* bg = (const float*)d_in[2];
  const float* W1 = (const float*)d_in[3];
  const float* b1 = (const float*)d_in[4];
  const float* W2 = (const float*)d_in[5];
  const float* b2 = (const float*)d_in[6];
  float* out = (float*)d_out;
  char* ws = (char*)d_ws;

  int*   counts   = (int*)ws;
  int*   pairTok  = (int*)(ws + OFF_PTOK);
  float* pairProb = (float*)(ws + OFF_PPROB);
  int*   sched    = (int*)(ws + OFF_SCHED);
  bf16*  Xbf      = (bf16*)(ws + OFF_XBF);
  bf16*  W2t      = (bf16*)(ws + OFF_W2T);
  bf16*  Hbuf     = (bf16*)(ws + OFF_HBUF);
  bf16*  W1t      = (bf16*)(ws + OFF_W1T);

  hipMemsetAsync(counts, 0, 64, stream);
  hipMemsetAsync(out, 0, (size_t)NTOK * D_IN * sizeof(float), stream);
  // W1 [E][1024][4096] -> W1t [E][4096][1024]
  transpose_cvt<<<dim3(H_DIM / 64, D_IN / 64, E_NUM), 256, 0, stream>>>(W1, W1t, D_IN, H_DIM);
  // W2 [E][4096][1024] -> W2t [E][1024][4096]
  transpose_cvt<<<dim3(D_IN / 64, H_DIM / 64, E_NUM), 256, 0, stream>>>(W2, W2t, H_DIM, D_IN);
  router_kernel<<<NTOK / 32, 256, 0, stream>>>(x, Wg, bg, Xbf, counts, pairTok, pairProb);
  sched_kernel<<<1, 64, 0, stream>>>(counts, sched);
  // GEMM1: 8 XCD-chunks x 17 supertiles x 32 blocks = 4352
  gemm_kernel<0, D_IN, H_DIM, 1><<<8 * 17 * 32, 256, 0, stream>>>(
      Xbf, W1t, b1, counts, pairTok, pairProb, sched, Hbuf, nullptr);
  // GEMM2: 8 XCD-chunks x 9 supertiles x 32 blocks = 2304 (68 real supertiles)
  gemm_kernel<1, H_DIM, D_IN, 2><<<8 * 9 * 32, 256, 0, stream>>>(
      Hbuf, W2t, b2, counts, pairTok, pairProb, sched, nullptr, out);
}